// Round 7
// baseline (1445.599 us; speedup 1.0000x reference)
//
#include <hip/hip_runtime.h>

typedef unsigned short u16;
typedef __attribute__((ext_vector_type(8))) short short8;   // 8 bf16 (4 VGPRs)
typedef __attribute__((ext_vector_type(4))) float f32x4;

__device__ __forceinline__ u16 f2bf(float f) {
    unsigned int x = __float_as_uint(f);
    unsigned int r = x + 0x7fffu + ((x >> 16) & 1u);
    return (u16)(r >> 16);
}
__device__ __forceinline__ unsigned int pk2(float lo, float hi) {
    return ((unsigned int)f2bf(hi) << 16) | (unsigned int)f2bf(lo);
}
__device__ __forceinline__ float2 bf2x(unsigned int d) {
    float2 r;
    r.x = __uint_as_float(d << 16);
    r.y = __uint_as_float(d & 0xffff0000u);
    return r;
}
__device__ __forceinline__ void bf8x(uint4 v, float* o) {
    float2 a = bf2x(v.x); o[0] = a.x; o[1] = a.y;
    float2 b = bf2x(v.y); o[2] = b.x; o[3] = b.y;
    float2 c = bf2x(v.z); o[4] = c.x; o[5] = c.y;
    float2 d = bf2x(v.w); o[6] = d.x; o[7] = d.y;
}

#define CC 96
#define SS 16
#define GG 6
#define BN_INV 0.99999500003749969f  // 1/sqrt(1+1e-5)
#define ABLK 768                     // 3 blocks/CU, fully resident
#define TOTW (ABLK * 4)

// gWB image (dwords, bf16 pairs): [0..2495] Wp2 even cols (row c2=channel/2,
// stride 52 dw, 48 used), [2496..4991] Wp2 odd cols, [4992..5303] Wpw rows.
#define WB_ODD 2496
#define WB_WPW 4992
#define WB_TOT 5304

// ---------------- kernel 0: prep (weights repack + tiny precompute) ----------------
__global__ __launch_bounds__(256) void prep_kernel(
    const float* __restrict__ Wq, const float* __restrict__ Wk, const float* __restrict__ Wv,
    const float* __restrict__ Wp2, const float* __restrict__ Ww1,
    const float* __restrict__ bp2, const float* __restrict__ bw1,
    u16* __restrict__ WcatT, unsigned int* __restrict__ gWB, float* __restrict__ cvec)
{
    int t = blockIdx.x * 256 + threadIdx.x;
    if (t < 13824) {
        // WcatT[c][j] bf16, row-major [288][96]; dword idx = c*48 + j2
        int c = t / 48, j2 = t % 48;
        const float* src = (c < 96) ? Wq : (c < 192) ? Wk : Wv;
        int cc = c % 96;
        float a = src[(2 * j2) * CC + cc];
        float b = src[(2 * j2 + 1) * CC + cc];
        ((unsigned int*)WcatT)[t] = pk2(a, b);
    } else if (t < 13824 + WB_TOT) {
        int i = t - 13824;
        if (i < WB_WPW) {
            int arr = i / WB_ODD;            // 0 = even channels, 1 = odd
            int r = i % WB_ODD;
            int c2 = r / 52, rr = r % 52;
            unsigned int d = 0;
            if (rr < 48) {
                int c = 2 * c2 + arr;
                d = pk2(Wp2[(2 * rr) * CC + c], Wp2[(2 * rr + 1) * CC + c]);
            }
            gWB[i] = d;
        } else {
            int r = i - WB_WPW;
            int g = r / 52, rr = r % 52;
            unsigned int d = 0;
            if (rr < 48) {
                float a = 0.f, b = 0.f;
                for (int c = 0; c < CC; ++c) {
                    float wg = Ww1[c * GG + g];
                    a = fmaf(Wp2[(2 * rr) * CC + c], wg, a);
                    b = fmaf(Wp2[(2 * rr + 1) * CC + c], wg, b);
                }
                d = pk2(a, b);
            }
            gWB[i] = d;
        }
    } else if (t < 13824 + WB_TOT + GG) {
        int g = t - (13824 + WB_TOT);
        float acc = bw1[g];
        for (int c = 0; c < CC; ++c)
            acc = fmaf(bp2[c], Ww1[c * GG + g], acc);
        cvec[g] = acc;
    }
}

// ---------------- kernel 1: fused q|k|v MFMA GEMM + epilogue ----------------
#define SBS 104
__global__ __launch_bounds__(256, 2) void gemm_qkv(
    const float* __restrict__ feat, const u16* __restrict__ WcatT,
    const float* __restrict__ bq, const float* __restrict__ gq, const float* __restrict__ betaq,
    const float* __restrict__ bk, const float* __restrict__ gk, const float* __restrict__ betak,
    const float* __restrict__ bv, const float* __restrict__ Ww1,
    u16* __restrict__ v_bf, float* __restrict__ KW1, float* __restrict__ qW1, int N)
{
    __shared__ u16 sB[288 * SBS];
    const int t = threadIdx.x;

    for (int i = t; i < 288 * 12; i += 256) {
        int row = i / 12, c8 = i % 12;
        *(float4*)(sB + row * SBS + c8 * 8) = *(const float4*)(WcatT + row * CC + c8 * 8);
    }
    __syncthreads();

    const int wave = t >> 6, lane = t & 63;
    const int m = lane & 15, quad = lane >> 4;
    const int rowbase = blockIdx.x * 64 + wave * 16;

    int arow = rowbase + m;
    if (arow >= N) arow = 0;

    short8 a[3];
    #pragma unroll
    for (int kk = 0; kk < 3; ++kk) {
        const float* fr = feat + (size_t)arow * CC + kk * 32 + quad * 8;
        float4 fa = *(const float4*)(fr);
        float4 fb = *(const float4*)(fr + 4);
        union { short8 v; unsigned int u[4]; } pk;
        pk.u[0] = pk2(fa.x, fa.y); pk.u[1] = pk2(fa.z, fa.w);
        pk.u[2] = pk2(fb.x, fb.y); pk.u[3] = pk2(fb.z, fb.w);
        a[kk] = pk.v;
    }

    f32x4 acc[18];
    #pragma unroll
    for (int nt = 0; nt < 18; ++nt) acc[nt] = (f32x4){0.f, 0.f, 0.f, 0.f};

    #pragma unroll
    for (int kk = 0; kk < 3; ++kk) {
        #pragma unroll
        for (int nt = 0; nt < 18; ++nt) {
            short8 b = *(const short8*)(sB + (nt * 16 + m) * SBS + kk * 32 + quad * 8);
            acc[nt] = __builtin_amdgcn_mfma_f32_16x16x32_bf16(a[kk], b, acc[nt], 0, 0, 0);
        }
    }

    int orow[4];
    #pragma unroll
    for (int i = 0; i < 4; ++i) orow[i] = rowbase + quad * 4 + i;
    const int cloc = m;

    #pragma unroll
    for (int nt6 = 0; nt6 < 6; ++nt6) {
        int c = nt6 * 16 + cloc;
        float bvv = bv[c];
        #pragma unroll
        for (int i = 0; i < 4; ++i)
            if (orow[i] < N)
                v_bf[(size_t)orow[i] * CC + c] = f2bf(acc[12 + nt6][i] + bvv);
    }

    #pragma unroll
    for (int mat = 0; mat < 2; ++mat) {
        const float* bb_ = mat ? bk : bq;
        const float* gg_ = mat ? gk : gq;
        const float* be_ = mat ? betak : betaq;
        float red[4][6];
        #pragma unroll
        for (int i = 0; i < 4; ++i)
            #pragma unroll
            for (int g = 0; g < 6; ++g) red[i][g] = 0.f;

        #pragma unroll
        for (int nt6 = 0; nt6 < 6; ++nt6) {
            int nt = mat * 6 + nt6;
            int c = nt6 * 16 + cloc;
            float bb = bb_[c], sc = gg_[c] * BN_INV, be = be_[c];
            float w1r[6];
            #pragma unroll
            for (int g = 0; g < 6; ++g) w1r[g] = Ww1[c * GG + g];
            #pragma unroll
            for (int i = 0; i < 4; ++i) {
                float act = fmaxf(0.f, fmaf(acc[nt][i] + bb, sc, be));
                #pragma unroll
                for (int g = 0; g < 6; ++g)
                    red[i][g] = fmaf(act, w1r[g], red[i][g]);
            }
        }
        #pragma unroll
        for (int st = 1; st < 16; st <<= 1)
            #pragma unroll
            for (int i = 0; i < 4; ++i)
                #pragma unroll
                for (int g = 0; g < 6; ++g)
                    red[i][g] += __shfl_xor(red[i][g], st);

        float* dst = mat ? KW1 : qW1;
        #pragma unroll
        for (int g = 0; g < 6; ++g)
            if (cloc == g)
                #pragma unroll
                for (int i = 0; i < 4; ++i)
                    if (orow[i] < N)
                        dst[(size_t)orow[i] * 8 + g] = red[i][g];
    }
}

// ---------------- kernel 2: attention v4 (bank-exact layouts, 3 blk/CU) ----------------
__global__ __launch_bounds__(256, 3) void attn_kernel(
    const float* __restrict__ coord, const int* __restrict__ ref,
    const float* __restrict__ Wp1, const float* __restrict__ bp1, const float* __restrict__ gp, const float* __restrict__ betap,
    const float* __restrict__ bp2,
    const float* __restrict__ gw, const float* __restrict__ betaw,
    const float* __restrict__ Ww2, const float* __restrict__ bw2,
    const u16* __restrict__ v_bf, const float* __restrict__ KW1, const float* __restrict__ qW1,
    const unsigned int* __restrict__ gWB, const float* __restrict__ cvec,
    float* __restrict__ out, int N)
{
    __shared__ __align__(16) unsigned int sWB[WB_TOT];  // 21216 B
    __shared__ __align__(16) unsigned int shh[4][832];  // h bf16 pairs [s*52 + L]
    __shared__ __align__(16) uint4 swt[4][SS];          // packed softmax weights per s
    __shared__ __align__(16) float sHs[4][600];         // Hsum fp32 [g*100 + 2L]
    __shared__ __align__(16) float4 sposx[4][SS];       // pos xyz
    __shared__ int sidxx[4][SS];
    // total 46432 B -> 3 blocks/CU

    const int t = threadIdx.x;
    for (int i = t; i < WB_TOT; i += 256) sWB[i] = gWB[i];
    __syncthreads();   // only block barrier

    const int w = t >> 6, lane = t & 63;
    const int wid = blockIdx.x * 4 + w;
    unsigned int* shw = shh[w];
    uint4* swtw = swt[w];
    float* sHsw = sHs[w];
    float4* sposw = sposx[w];
    int* sidxw = sidxx[w];

    const int  L = (lane < 48) ? lane : 47;
    const bool actv = lane < 48;
    const int  cA = 2 * L;
    const int  gL = L >> 3;
    const int  s16 = lane & 15, qq = lane >> 4;

    const float w1xA = Wp1[cA], w1yA = Wp1[CC + cA], w1zA = Wp1[2 * CC + cA];
    const float w1xB = Wp1[cA + 1], w1yB = Wp1[CC + cA + 1], w1zB = Wp1[2 * CC + cA + 1];
    const float b1A = bp1[cA], spA = gp[cA] * BN_INV, btA = betap[cA];
    const float b1B = bp1[cA + 1], spB = gp[cA + 1] * BN_INV, btB = betap[cA + 1];
    const float bpA = bp2[cA], bpB = bp2[cA + 1];

    for (int n = wid; n < N; n += TOTW) {
        // ---- prefetch chain: idx -> v loads; coord/k/q on lanes<16 ----
        int idxreg = 0;
        if (lane < SS) {
            idxreg = ref[n * SS + s16];
            sidxw[s16] = idxreg;
        }
        unsigned int vpre[SS];
        #pragma unroll
        for (int s = 0; s < SS; ++s) {
            int jj = sidxw[s];                       // wave-private, in-order DS
            vpre[s] = *(const unsigned int*)(v_bf + (size_t)jj * CC + cA);
        }
        float4 kAv = {0,0,0,0}; float2 kBv = {0,0};
        float4 qAv = {0,0,0,0}; float2 qBv = {0,0};
        if (lane < SS) {
            int j = idxreg;
            float4 P;
            P.x = coord[j * 3 + 0] - coord[n * 3 + 0];
            P.y = coord[j * 3 + 1] - coord[n * 3 + 1];
            P.z = coord[j * 3 + 2] - coord[n * 3 + 2];
            P.w = 0.f;
            sposw[s16] = P;
            const float* kr = KW1 + (size_t)idxreg * 8;
            kAv = *(const float4*)kr; kBv = *(const float2*)(kr + 4);
            const float* qr = qW1 + (size_t)n * 8;
            qAv = *(const float4*)qr; qBv = *(const float2*)(qr + 4);
        }

        // ---- stage 1: h = relu(bn(pos@Wp1)) -> packed bf16 pairs ----
        if (actv) {
            #pragma unroll
            for (int s = 0; s < SS; ++s) {
                float4 P = sposw[s];                 // broadcast b128
                float hA = fmaf(P.x, w1xA, fmaf(P.y, w1yA, fmaf(P.z, w1zA, b1A)));
                hA = fmaxf(0.f, fmaf(hA, spA, btA));
                float hB = fmaf(P.x, w1xB, fmaf(P.y, w1yB, fmaf(P.z, w1zB, b1B)));
                hB = fmaxf(0.f, fmaf(hB, spB, btB));
                shw[s * 52 + L] = pk2(hA, hB);
            }
        }

        // ---- stage 2: logits (4 lanes per neighbor, 24-ch slices) ----
        {
            const unsigned int* hrow = shw + 52 * s16 + 12 * qq;
            float hg[24];
            bf8x(*(const uint4*)(hrow), hg);
            bf8x(*(const uint4*)(hrow + 4), hg + 8);
            bf8x(*(const uint4*)(hrow + 8), hg + 16);

            float acc[GG];
            #pragma unroll
            for (int g = 0; g < GG; ++g) {
                const unsigned int* wr = sWB + WB_WPW + g * 52 + 12 * qq;
                float wg[24];
                bf8x(*(const uint4*)(wr), wg);
                bf8x(*(const uint4*)(wr + 4), wg + 8);
                bf8x(*(const uint4*)(wr + 8), wg + 16);
                float a = 0.f;
                #pragma unroll
                for (int u = 0; u < 24; ++u)
                    a = fmaf(hg[u], wg[u], a);
                acc[g] = a;
            }
            #pragma unroll
            for (int g = 0; g < GG; ++g) {
                acc[g] += __shfl_xor(acc[g], 16);
                acc[g] += __shfl_xor(acc[g], 32);
            }

            if (lane < SS) {
                float tv[GG];
                tv[0] = acc[0] + kAv.x - qAv.x + cvec[0];
                tv[1] = acc[1] + kAv.y - qAv.y + cvec[1];
                tv[2] = acc[2] + kAv.z - qAv.z + cvec[2];
                tv[3] = acc[3] + kAv.w - qAv.w + cvec[3];
                tv[4] = acc[4] + kBv.x - qBv.x + cvec[4];
                tv[5] = acc[5] + kBv.y - qBv.y + cvec[5];
                float a6[GG];
                #pragma unroll
                for (int g = 0; g < GG; ++g)
                    a6[g] = fmaxf(0.f, fmaf(tv[g], gw[g] * BN_INV, betaw[g]));
                // logits -> exp (no max-subtract: |logit| << 1 for this model) -> wave-16 sum
                float e[GG];
                #pragma unroll
                for (int gg2 = 0; gg2 < GG; ++gg2) {
                    float lv = bw2[gg2];
                    #pragma unroll
                    for (int g2 = 0; g2 < GG; ++g2)
                        lv = fmaf(a6[g2], Ww2[g2 * GG + gg2], lv);
                    e[gg2] = __expf(lv);
                }
                float wgt[GG];
                #pragma unroll
                for (int g = 0; g < GG; ++g) {
                    float ssum = e[g];
                    ssum += __shfl_xor(ssum, 1);
                    ssum += __shfl_xor(ssum, 2);
                    ssum += __shfl_xor(ssum, 4);
                    ssum += __shfl_xor(ssum, 8);
                    wgt[g] = e[g] / ssum;
                }
                uint4 wt;
                wt.x = pk2(wgt[0], wgt[1]);
                wt.y = pk2(wgt[2], wgt[3]);
                wt.z = pk2(wgt[4], wgt[5]);
                wt.w = 0u;
                swtw[s16] = wt;
            }
        }

        // ---- stage 3+4: Hsum + v-part fused ----
        float accA = bpA, accB = bpB;
        {
            float hsA[GG] = {0.f,0.f,0.f,0.f,0.f,0.f};
            float hsB[GG] = {0.f,0.f,0.f,0.f,0.f,0.f};
            #pragma unroll
            for (int s = 0; s < SS; ++s) {
                uint4 wt = swtw[s];                  // broadcast b128
                float2 w01 = bf2x(wt.x), w23 = bf2x(wt.y), w45 = bf2x(wt.z);
                float2 h2 = bf2x(shw[s * 52 + L]);
                hsA[0] = fmaf(w01.x, h2.x, hsA[0]); hsB[0] = fmaf(w01.x, h2.y, hsB[0]);
                hsA[1] = fmaf(w01.y, h2.x, hsA[1]); hsB[1] = fmaf(w01.y, h2.y, hsB[1]);
                hsA[2] = fmaf(w23.x, h2.x, hsA[2]); hsB[2] = fmaf(w23.x, h2.y, hsB[2]);
                hsA[3] = fmaf(w23.y, h2.x, hsA[3]); hsB[3] = fmaf(w23.y, h2.y, hsB[3]);
                hsA[4] = fmaf(w45.x, h2.x, hsA[4]); hsB[4] = fmaf(w45.x, h2.y, hsB[4]);
                hsA[5] = fmaf(w45.y, h2.x, hsA[5]); hsB[5] = fmaf(w45.y, h2.y, hsB[5]);
                float wsel = (gL < 2) ? (gL == 0 ? w01.x : w01.y)
                           : (gL < 4) ? (gL == 2 ? w23.x : w23.y)
                                      : (gL == 4 ? w45.x : w45.y);
                float2 v2 = bf2x(vpre[s]);
                accA = fmaf(v2.x, wsel, accA);
                accB = fmaf(v2.y, wsel, accB);
            }
            if (actv) {
                #pragma unroll
                for (int g = 0; g < GG; ++g)
                    *(float2*)(sHsw + g * 100 + cA) = make_float2(hsA[g], hsB[g]);
            }
        }

        // ---- stage 5: out = v-part + Hsum[gL] @ Wp2 cols ----
        if (actv) {
            const float* hrg = sHsw + gL * 100;
            const unsigned int* wrE = sWB + L * 52;            // even channel cA
            const unsigned int* wrO = sWB + WB_ODD + L * 52;   // odd channel cA+1
            #pragma unroll
            for (int u = 0; u < 12; ++u) {
                float4 hb0 = *(const float4*)(hrg + 8 * u);
                float4 hb1 = *(const float4*)(hrg + 8 * u + 4);
                float we[8], wo[8];
                bf8x(*(const uint4*)(wrE + 4 * u), we);
                bf8x(*(const uint4*)(wrO + 4 * u), wo);
                accA = fmaf(hb0.x, we[0], accA); accB = fmaf(hb0.x, wo[0], accB);
                accA = fmaf(hb0.y, we[1], accA); accB = fmaf(hb0.y, wo[1], accB);
                accA = fmaf(hb0.z, we[2], accA); accB = fmaf(hb0.z, wo[2], accB);
                accA = fmaf(hb0.w, we[3], accA); accB = fmaf(hb0.w, wo[3], accB);
                accA = fmaf(hb1.x, we[4], accA); accB = fmaf(hb1.x, wo[4], accB);
                accA = fmaf(hb1.y, we[5], accA); accB = fmaf(hb1.y, wo[5], accB);
                accA = fmaf(hb1.z, we[6], accA); accB = fmaf(hb1.z, wo[6], accB);
                accA = fmaf(hb1.w, we[7], accA); accB = fmaf(hb1.w, wo[7], accB);
            }
            *(float2*)(out + (size_t)n * CC + cA) = make_float2(accA, accB);
        }
    }
}

extern "C" void kernel_launch(void* const* d_in, const int* in_sizes, int n_in,
                              void* d_out, int out_size, void* d_ws, size_t ws_size,
                              hipStream_t stream) {
    const float* feat  = (const float*)d_in[0];
    const float* coord = (const float*)d_in[1];
    const int*   ref   = (const int*)d_in[2];
    const float* Wq = (const float*)d_in[3],  *bq = (const float*)d_in[4],  *gq = (const float*)d_in[5],  *betaq = (const float*)d_in[6];
    const float* Wk = (const float*)d_in[7],  *bk = (const float*)d_in[8],  *gk = (const float*)d_in[9],  *betak = (const float*)d_in[10];
    const float* Wv = (const float*)d_in[11], *bv = (const float*)d_in[12];
    const float* Wp1 = (const float*)d_in[13], *bp1 = (const float*)d_in[14], *gp = (const float*)d_in[15], *betap = (const float*)d_in[16];
    const float* Wp2 = (const float*)d_in[17], *bp2 = (const float*)d_in[18];
    const float* Ww1 = (const float*)d_in[19], *bw1 = (const float*)d_in[20], *gw = (const float*)d_in[21], *betaw = (const float*)d_in[22];
    const float* Ww2 = (const float*)d_in[23], *bw2 = (const float*)d_in[24];

    const int N = in_sizes[0] / CC;   // 50000

    // workspace (~13 MB)
    float* wsf = (float*)d_ws;
    float* KW1 = wsf;                                  // N*8 f32
    float* qW1 = KW1 + (size_t)N * 8;                  // N*8 f32
    float* cvec = qW1 + (size_t)N * 8;                 // 6 (pad 32)
    unsigned int* gWB = (unsigned int*)(cvec + 32);    // 5304 (pad 5312)
    u16* WcatT = (u16*)(gWB + 5312);                   // 288*96 bf16
    u16* v_bf = WcatT + 288 * CC;                      // N*96 bf16

    const int prep_total = 13824 + WB_TOT + GG;
    prep_kernel<<<dim3((prep_total + 255) / 256), dim3(256), 0, stream>>>(
        Wq, Wk, Wv, Wp2, Ww1, bp2, bw1, WcatT, gWB, cvec);

    gemm_qkv<<<dim3((N + 63) / 64), dim3(256), 0, stream>>>(
        feat, WcatT, bq, gq, betaq, bk, gk, betak, bv, Ww1,
        v_bf, KW1, qW1, N);

    attn_kernel<<<dim3(ABLK), dim3(256), 0, stream>>>(
        coord, ref, Wp1, bp1, gp, betap, bp2, gw, betaw, Ww2, bw2,
        v_bf, KW1, qW1, gWB, cvec, (float*)d_out, N);
}

// Round 8
// 415.867 us; speedup vs baseline: 3.4761x; 3.4761x over previous
//
#include <hip/hip_runtime.h>

typedef unsigned short u16;
typedef __attribute__((ext_vector_type(8))) short short8;   // 8 bf16 (4 VGPRs)
typedef __attribute__((ext_vector_type(4))) float f32x4;

__device__ __forceinline__ u16 f2bf(float f) {
    unsigned int x = __float_as_uint(f);
    unsigned int r = x + 0x7fffu + ((x >> 16) & 1u);
    return (u16)(r >> 16);
}
__device__ __forceinline__ unsigned int pk2(float lo, float hi) {
    return ((unsigned int)f2bf(hi) << 16) | (unsigned int)f2bf(lo);
}
__device__ __forceinline__ float2 bf2x(unsigned int d) {
    float2 r;
    r.x = __uint_as_float(d << 16);
    r.y = __uint_as_float(d & 0xffff0000u);
    return r;
}
__device__ __forceinline__ void bf8x(uint4 v, float* o) {
    float2 a = bf2x(v.x); o[0] = a.x; o[1] = a.y;
    float2 b = bf2x(v.y); o[2] = b.x; o[3] = b.y;
    float2 c = bf2x(v.z); o[4] = c.x; o[5] = c.y;
    float2 d = bf2x(v.w); o[6] = d.x; o[7] = d.y;
}

#define CC 96
#define SS 16
#define GG 6
#define BN_INV 0.99999500003749969f  // 1/sqrt(1+1e-5)
#define ABLK 768
#define TOTW (ABLK * 4)

// gWB image (dwords, bf16 pairs): [0..2495] Wp2 even cols (row c2=channel/2,
// stride 52 dw, 48 used), [2496..4991] Wp2 odd cols, [4992..5303] Wpw rows.
#define WB_ODD 2496
#define WB_WPW 4992
#define WB_TOT 5304

// ---------------- kernel 0: prep (weights repack + tiny precompute) ----------------
__global__ __launch_bounds__(256) void prep_kernel(
    const float* __restrict__ Wq, const float* __restrict__ Wk, const float* __restrict__ Wv,
    const float* __restrict__ Wp2, const float* __restrict__ Ww1,
    const float* __restrict__ bp2, const float* __restrict__ bw1,
    u16* __restrict__ WcatT, unsigned int* __restrict__ gWB, float* __restrict__ cvec)
{
    int t = blockIdx.x * 256 + threadIdx.x;
    if (t < 13824) {
        // WcatT[c][j] bf16, row-major [288][96]; dword idx = c*48 + j2
        int c = t / 48, j2 = t % 48;
        const float* src = (c < 96) ? Wq : (c < 192) ? Wk : Wv;
        int cc = c % 96;
        float a = src[(2 * j2) * CC + cc];
        float b = src[(2 * j2 + 1) * CC + cc];
        ((unsigned int*)WcatT)[t] = pk2(a, b);
    } else if (t < 13824 + WB_TOT) {
        int i = t - 13824;
        if (i < WB_WPW) {
            int arr = i / WB_ODD;            // 0 = even channels, 1 = odd
            int r = i % WB_ODD;
            int c2 = r / 52, rr = r % 52;
            unsigned int d = 0;
            if (rr < 48) {
                int c = 2 * c2 + arr;
                d = pk2(Wp2[(2 * rr) * CC + c], Wp2[(2 * rr + 1) * CC + c]);
            }
            gWB[i] = d;
        } else {
            int r = i - WB_WPW;
            int g = r / 52, rr = r % 52;
            unsigned int d = 0;
            if (rr < 48) {
                float a = 0.f, b = 0.f;
                for (int c = 0; c < CC; ++c) {
                    float wg = Ww1[c * GG + g];
                    a = fmaf(Wp2[(2 * rr) * CC + c], wg, a);
                    b = fmaf(Wp2[(2 * rr + 1) * CC + c], wg, b);
                }
                d = pk2(a, b);
            }
            gWB[i] = d;
        }
    } else if (t < 13824 + WB_TOT + GG) {
        int g = t - (13824 + WB_TOT);
        float acc = bw1[g];
        for (int c = 0; c < CC; ++c)
            acc = fmaf(bp2[c], Ww1[c * GG + g], acc);
        cvec[g] = acc;
    }
}

// ---------------- kernel 0b: feat -> bf16 (r6-proven) ----------------
__global__ __launch_bounds__(256) void fcvt_kernel(
    const float* __restrict__ feat, u16* __restrict__ featB, int total4)
{
    int i = blockIdx.x * 256 + threadIdx.x;
    if (i < total4) {
        float4 v = *(const float4*)(feat + (size_t)i * 4);
        ushort4 o;
        o.x = f2bf(v.x); o.y = f2bf(v.y); o.z = f2bf(v.z); o.w = f2bf(v.w);
        *(ushort4*)(featB + (size_t)i * 4) = o;
    }
}

// ---------------- kernel 1: fused q|k|v MFMA GEMM + epilogue (r6-proven) ----------------
#define SBS 104
__global__ __launch_bounds__(256, 2) void gemm_qkv(
    const u16* __restrict__ featB, const u16* __restrict__ WcatT,
    const float* __restrict__ bq, const float* __restrict__ gq, const float* __restrict__ betaq,
    const float* __restrict__ bk, const float* __restrict__ gk, const float* __restrict__ betak,
    const float* __restrict__ bv, const float* __restrict__ Ww1,
    u16* __restrict__ v_bf, float* __restrict__ KW1, float* __restrict__ qW1, int N)
{
    __shared__ u16 sB[288 * SBS];
    const int t = threadIdx.x;

    for (int i = t; i < 288 * 12; i += 256) {
        int row = i / 12, c8 = i % 12;
        *(float4*)(sB + row * SBS + c8 * 8) = *(const float4*)(WcatT + row * CC + c8 * 8);
    }
    __syncthreads();

    const int wave = t >> 6, lane = t & 63;
    const int m = lane & 15, quad = lane >> 4;
    const int rowbase = blockIdx.x * 64 + wave * 16;

    int arow = rowbase + m;
    if (arow >= N) arow = 0;

    short8 a[3];
    #pragma unroll
    for (int kk = 0; kk < 3; ++kk)
        a[kk] = *(const short8*)(featB + (size_t)arow * CC + kk * 32 + quad * 8);

    f32x4 acc[18];
    #pragma unroll
    for (int nt = 0; nt < 18; ++nt) acc[nt] = (f32x4){0.f, 0.f, 0.f, 0.f};

    #pragma unroll
    for (int kk = 0; kk < 3; ++kk) {
        #pragma unroll
        for (int nt = 0; nt < 18; ++nt) {
            short8 b = *(const short8*)(sB + (nt * 16 + m) * SBS + kk * 32 + quad * 8);
            acc[nt] = __builtin_amdgcn_mfma_f32_16x16x32_bf16(a[kk], b, acc[nt], 0, 0, 0);
        }
    }

    int orow[4];
    #pragma unroll
    for (int i = 0; i < 4; ++i) orow[i] = rowbase + quad * 4 + i;
    const int cloc = m;

    #pragma unroll
    for (int nt6 = 0; nt6 < 6; ++nt6) {
        int c = nt6 * 16 + cloc;
        float bvv = bv[c];
        #pragma unroll
        for (int i = 0; i < 4; ++i)
            if (orow[i] < N)
                v_bf[(size_t)orow[i] * CC + c] = f2bf(acc[12 + nt6][i] + bvv);
    }

    #pragma unroll
    for (int mat = 0; mat < 2; ++mat) {
        const float* bb_ = mat ? bk : bq;
        const float* gg_ = mat ? gk : gq;
        const float* be_ = mat ? betak : betaq;
        float red[4][6];
        #pragma unroll
        for (int i = 0; i < 4; ++i)
            #pragma unroll
            for (int g = 0; g < 6; ++g) red[i][g] = 0.f;

        #pragma unroll
        for (int nt6 = 0; nt6 < 6; ++nt6) {
            int nt = mat * 6 + nt6;
            int c = nt6 * 16 + cloc;
            float bb = bb_[c], sc = gg_[c] * BN_INV, be = be_[c];
            float w1r[6];
            #pragma unroll
            for (int g = 0; g < 6; ++g) w1r[g] = Ww1[c * GG + g];
            #pragma unroll
            for (int i = 0; i < 4; ++i) {
                float act = fmaxf(0.f, fmaf(acc[nt][i] + bb, sc, be));
                #pragma unroll
                for (int g = 0; g < 6; ++g)
                    red[i][g] = fmaf(act, w1r[g], red[i][g]);
            }
        }
        #pragma unroll
        for (int st = 1; st < 16; st <<= 1)
            #pragma unroll
            for (int i = 0; i < 4; ++i)
                #pragma unroll
                for (int g = 0; g < 6; ++g)
                    red[i][g] += __shfl_xor(red[i][g], st);

        float* dst = mat ? KW1 : qW1;
        #pragma unroll
        for (int g = 0; g < 6; ++g)
            if (cloc == g)
                #pragma unroll
                for (int i = 0; i < 4; ++i)
                    if (orow[i] < N)
                        dst[(size_t)orow[i] * 8 + g] = red[i][g];
    }
}

// ---------------- kernel 2: attention v4b — r7 structure, NO min-waves forcing ----------------
__global__ __launch_bounds__(256) void attn_kernel(
    const float* __restrict__ coord, const int* __restrict__ ref,
    const float* __restrict__ Wp1, const float* __restrict__ bp1, const float* __restrict__ gp, const float* __restrict__ betap,
    const float* __restrict__ bp2,
    const float* __restrict__ gw, const float* __restrict__ betaw,
    const float* __restrict__ Ww2, const float* __restrict__ bw2,
    const u16* __restrict__ v_bf, const float* __restrict__ KW1, const float* __restrict__ qW1,
    const unsigned int* __restrict__ gWB, const float* __restrict__ cvec,
    float* __restrict__ out, int N)
{
    __shared__ __align__(16) unsigned int sWB[WB_TOT];  // 21216 B
    __shared__ __align__(16) unsigned int shh[4][832];  // h bf16 pairs [s*52 + L]
    __shared__ __align__(16) uint4 swt[4][SS];          // packed softmax weights per s
    __shared__ __align__(16) float sHs[4][600];         // Hsum fp32 [g*100 + 2L]
    __shared__ __align__(16) float4 sposx[4][SS];
    __shared__ int sidxx[4][SS];

    const int t = threadIdx.x;
    for (int i = t; i < WB_TOT; i += 256) sWB[i] = gWB[i];
    __syncthreads();   // only block barrier

    const int w = t >> 6, lane = t & 63;
    const int wid = blockIdx.x * 4 + w;
    unsigned int* shw = shh[w];
    uint4* swtw = swt[w];
    float* sHsw = sHs[w];
    float4* sposw = sposx[w];
    int* sidxw = sidxx[w];

    const int  L = (lane < 48) ? lane : 47;
    const bool actv = lane < 48;
    const int  cA = 2 * L;
    const int  gL = L >> 3;
    const int  s16 = lane & 15, qq = lane >> 4;

    const float w1xA = Wp1[cA], w1yA = Wp1[CC + cA], w1zA = Wp1[2 * CC + cA];
    const float w1xB = Wp1[cA + 1], w1yB = Wp1[CC + cA + 1], w1zB = Wp1[2 * CC + cA + 1];
    const float b1A = bp1[cA], spA = gp[cA] * BN_INV, btA = betap[cA];
    const float b1B = bp1[cA + 1], spB = gp[cA + 1] * BN_INV, btB = betap[cA + 1];
    const float bpA = bp2[cA], bpB = bp2[cA + 1];

    for (int n = wid; n < N; n += TOTW) {
        // ---- prefetch chain ----
        int idxreg = 0;
        if (lane < SS) {
            idxreg = ref[n * SS + s16];
            sidxw[s16] = idxreg;
        }
        unsigned int vpre[SS];
        #pragma unroll
        for (int s = 0; s < SS; ++s) {
            int jj = sidxw[s];                       // wave-private, in-order DS
            vpre[s] = *(const unsigned int*)(v_bf + (size_t)jj * CC + cA);
        }
        float4 kAv = {0,0,0,0}; float2 kBv = {0,0};
        float4 qAv = {0,0,0,0}; float2 qBv = {0,0};
        if (lane < SS) {
            int j = idxreg;
            float4 P;
            P.x = coord[j * 3 + 0] - coord[n * 3 + 0];
            P.y = coord[j * 3 + 1] - coord[n * 3 + 1];
            P.z = coord[j * 3 + 2] - coord[n * 3 + 2];
            P.w = 0.f;
            sposw[s16] = P;
            const float* kr = KW1 + (size_t)idxreg * 8;
            kAv = *(const float4*)kr; kBv = *(const float2*)(kr + 4);
            const float* qr = qW1 + (size_t)n * 8;
            qAv = *(const float4*)qr; qBv = *(const float2*)(qr + 4);
        }

        // ---- stage 1: h = relu(bn(pos@Wp1)) -> packed bf16 pairs ----
        if (actv) {
            #pragma unroll
            for (int s = 0; s < SS; ++s) {
                float4 P = sposw[s];                 // broadcast b128
                float hA = fmaf(P.x, w1xA, fmaf(P.y, w1yA, fmaf(P.z, w1zA, b1A)));
                hA = fmaxf(0.f, fmaf(hA, spA, btA));
                float hB = fmaf(P.x, w1xB, fmaf(P.y, w1yB, fmaf(P.z, w1zB, b1B)));
                hB = fmaxf(0.f, fmaf(hB, spB, btB));
                shw[s * 52 + L] = pk2(hA, hB);
            }
        }

        // ---- stage 2: logits (4 lanes per neighbor, 24-ch slices) ----
        {
            const unsigned int* hrow = shw + 52 * s16 + 12 * qq;
            float hg[24];
            bf8x(*(const uint4*)(hrow), hg);
            bf8x(*(const uint4*)(hrow + 4), hg + 8);
            bf8x(*(const uint4*)(hrow + 8), hg + 16);

            float acc[GG];
            #pragma unroll
            for (int g = 0; g < GG; ++g) {
                const unsigned int* wr = sWB + WB_WPW + g * 52 + 12 * qq;
                float wg[24];
                bf8x(*(const uint4*)(wr), wg);
                bf8x(*(const uint4*)(wr + 4), wg + 8);
                bf8x(*(const uint4*)(wr + 8), wg + 16);
                float a = 0.f;
                #pragma unroll
                for (int u = 0; u < 24; ++u)
                    a = fmaf(hg[u], wg[u], a);
                acc[g] = a;
            }
            #pragma unroll
            for (int g = 0; g < GG; ++g) {
                acc[g] += __shfl_xor(acc[g], 16);
                acc[g] += __shfl_xor(acc[g], 32);
            }

            if (lane < SS) {
                float tv[GG];
                tv[0] = acc[0] + kAv.x - qAv.x + cvec[0];
                tv[1] = acc[1] + kAv.y - qAv.y + cvec[1];
                tv[2] = acc[2] + kAv.z - qAv.z + cvec[2];
                tv[3] = acc[3] + kAv.w - qAv.w + cvec[3];
                tv[4] = acc[4] + kBv.x - qBv.x + cvec[4];
                tv[5] = acc[5] + kBv.y - qBv.y + cvec[5];
                float a6[GG];
                #pragma unroll
                for (int g = 0; g < GG; ++g)
                    a6[g] = fmaxf(0.f, fmaf(tv[g], gw[g] * BN_INV, betaw[g]));
                float e[GG];
                #pragma unroll
                for (int gg2 = 0; gg2 < GG; ++gg2) {
                    float lv = bw2[gg2];
                    #pragma unroll
                    for (int g2 = 0; g2 < GG; ++g2)
                        lv = fmaf(a6[g2], Ww2[g2 * GG + gg2], lv);
                    e[gg2] = __expf(lv);
                }
                float wgt[GG];
                #pragma unroll
                for (int g = 0; g < GG; ++g) {
                    float ssum = e[g];
                    ssum += __shfl_xor(ssum, 1);
                    ssum += __shfl_xor(ssum, 2);
                    ssum += __shfl_xor(ssum, 4);
                    ssum += __shfl_xor(ssum, 8);
                    wgt[g] = e[g] / ssum;
                }
                uint4 wt;
                wt.x = pk2(wgt[0], wgt[1]);
                wt.y = pk2(wgt[2], wgt[3]);
                wt.z = pk2(wgt[4], wgt[5]);
                wt.w = 0u;
                swtw[s16] = wt;
            }
        }

        // ---- stage 3+4: Hsum + v-part fused ----
        float accA = bpA, accB = bpB;
        {
            float hsA[GG] = {0.f,0.f,0.f,0.f,0.f,0.f};
            float hsB[GG] = {0.f,0.f,0.f,0.f,0.f,0.f};
            #pragma unroll
            for (int s = 0; s < SS; ++s) {
                uint4 wt = swtw[s];                  // broadcast b128
                float2 w01 = bf2x(wt.x), w23 = bf2x(wt.y), w45 = bf2x(wt.z);
                float2 h2 = bf2x(shw[s * 52 + L]);
                hsA[0] = fmaf(w01.x, h2.x, hsA[0]); hsB[0] = fmaf(w01.x, h2.y, hsB[0]);
                hsA[1] = fmaf(w01.y, h2.x, hsA[1]); hsB[1] = fmaf(w01.y, h2.y, hsB[1]);
                hsA[2] = fmaf(w23.x, h2.x, hsA[2]); hsB[2] = fmaf(w23.x, h2.y, hsB[2]);
                hsA[3] = fmaf(w23.y, h2.x, hsA[3]); hsB[3] = fmaf(w23.y, h2.y, hsB[3]);
                hsA[4] = fmaf(w45.x, h2.x, hsA[4]); hsB[4] = fmaf(w45.x, h2.y, hsB[4]);
                hsA[5] = fmaf(w45.y, h2.x, hsA[5]); hsB[5] = fmaf(w45.y, h2.y, hsB[5]);
                float wsel = (gL < 2) ? (gL == 0 ? w01.x : w01.y)
                           : (gL < 4) ? (gL == 2 ? w23.x : w23.y)
                                      : (gL == 4 ? w45.x : w45.y);
                float2 v2 = bf2x(vpre[s]);
                accA = fmaf(v2.x, wsel, accA);
                accB = fmaf(v2.y, wsel, accB);
            }
            if (actv) {
                #pragma unroll
                for (int g = 0; g < GG; ++g)
                    *(float2*)(sHsw + g * 100 + cA) = make_float2(hsA[g], hsB[g]);
            }
        }

        // ---- stage 5: out = v-part + Hsum[gL] @ Wp2 cols ----
        if (actv) {
            const float* hrg = sHsw + gL * 100;
            const unsigned int* wrE = sWB + L * 52;            // even channel cA
            const unsigned int* wrO = sWB + WB_ODD + L * 52;   // odd channel cA+1
            #pragma unroll
            for (int u = 0; u < 12; ++u) {
                float4 hb0 = *(const float4*)(hrg + 8 * u);
                float4 hb1 = *(const float4*)(hrg + 8 * u + 4);
                float we[8], wo[8];
                bf8x(*(const uint4*)(wrE + 4 * u), we);
                bf8x(*(const uint4*)(wrO + 4 * u), wo);
                accA = fmaf(hb0.x, we[0], accA); accB = fmaf(hb0.x, wo[0], accB);
                accA = fmaf(hb0.y, we[1], accA); accB = fmaf(hb0.y, wo[1], accB);
                accA = fmaf(hb0.z, we[2], accA); accB = fmaf(hb0.z, wo[2], accB);
                accA = fmaf(hb0.w, we[3], accA); accB = fmaf(hb0.w, wo[3], accB);
                accA = fmaf(hb1.x, we[4], accA); accB = fmaf(hb1.x, wo[4], accB);
                accA = fmaf(hb1.y, we[5], accA); accB = fmaf(hb1.y, wo[5], accB);
                accA = fmaf(hb1.z, we[6], accA); accB = fmaf(hb1.z, wo[6], accB);
                accA = fmaf(hb1.w, we[7], accA); accB = fmaf(hb1.w, wo[7], accB);
            }
            *(float2*)(out + (size_t)n * CC + cA) = make_float2(accA, accB);
        }
    }
}

extern "C" void kernel_launch(void* const* d_in, const int* in_sizes, int n_in,
                              void* d_out, int out_size, void* d_ws, size_t ws_size,
                              hipStream_t stream) {
    const float* feat  = (const float*)d_in[0];
    const float* coord = (const float*)d_in[1];
    const int*   ref   = (const int*)d_in[2];
    const float* Wq = (const float*)d_in[3],  *bq = (const float*)d_in[4],  *gq = (const float*)d_in[5],  *betaq = (const float*)d_in[6];
    const float* Wk = (const float*)d_in[7],  *bk = (const float*)d_in[8],  *gk = (const float*)d_in[9],  *betak = (const float*)d_in[10];
    const float* Wv = (const float*)d_in[11], *bv = (const float*)d_in[12];
    const float* Wp1 = (const float*)d_in[13], *bp1 = (const float*)d_in[14], *gp = (const float*)d_in[15], *betap = (const float*)d_in[16];
    const float* Wp2 = (const float*)d_in[17], *bp2 = (const float*)d_in[18];
    const float* Ww1 = (const float*)d_in[19], *bw1 = (const float*)d_in[20], *gw = (const float*)d_in[21], *betaw = (const float*)d_in[22];
    const float* Ww2 = (const float*)d_in[23], *bw2 = (const float*)d_in[24];

    const int N = in_sizes[0] / CC;   // 50000

    // workspace (~23 MB)
    float* wsf = (float*)d_ws;
    float* KW1 = wsf;                                  // N*8 f32
    float* qW1 = KW1 + (size_t)N * 8;                  // N*8 f32
    float* cvec = qW1 + (size_t)N * 8;                 // 6 (pad 32)
    unsigned int* gWB = (unsigned int*)(cvec + 32);    // 5304 (pad 5312)
    u16* WcatT = (u16*)(gWB + 5312);                   // 288*96 bf16
    u16* featB = WcatT + 288 * CC;                     // N*96 bf16
    u16* v_bf = featB + (size_t)N * CC;                // N*96 bf16

    const int prep_total = 13824 + WB_TOT + GG;
    prep_kernel<<<dim3((prep_total + 255) / 256), dim3(256), 0, stream>>>(
        Wq, Wk, Wv, Wp2, Ww1, bp2, bw1, WcatT, gWB, cvec);

    const int total4 = N * CC / 4;
    fcvt_kernel<<<dim3((total4 + 255) / 256), dim3(256), 0, stream>>>(feat, featB, total4);

    gemm_qkv<<<dim3((N + 63) / 64), dim3(256), 0, stream>>>(
        featB, WcatT, bq, gq, betaq, bk, gk, betak, bv, Ww1,
        v_bf, KW1, qW1, N);

    attn_kernel<<<dim3(ABLK), dim3(256), 0, stream>>>(
        coord, ref, Wp1, bp1, gp, betap, bp2, gw, betaw, Ww2, bw2,
        v_bf, KW1, qW1, gWB, cvec, (float*)d_out, N);
}

// Round 9
// 410.408 us; speedup vs baseline: 3.5223x; 1.0133x over previous
//
#include <hip/hip_runtime.h>

typedef unsigned short u16;
typedef __attribute__((ext_vector_type(8))) short short8;   // 8 bf16 (4 VGPRs)
typedef __attribute__((ext_vector_type(4))) float f32x4;

__device__ __forceinline__ u16 f2bf(float f) {
    unsigned int x = __float_as_uint(f);
    unsigned int r = x + 0x7fffu + ((x >> 16) & 1u);
    return (u16)(r >> 16);
}
__device__ __forceinline__ unsigned int pk2(float lo, float hi) {
    return ((unsigned int)f2bf(hi) << 16) | (unsigned int)f2bf(lo);
}
__device__ __forceinline__ float2 bf2x(unsigned int d) {
    float2 r;
    r.x = __uint_as_float(d << 16);
    r.y = __uint_as_float(d & 0xffff0000u);
    return r;
}
__device__ __forceinline__ void bf8x(uint4 v, float* o) {
    float2 a = bf2x(v.x); o[0] = a.x; o[1] = a.y;
    float2 b = bf2x(v.y); o[2] = b.x; o[3] = b.y;
    float2 c = bf2x(v.z); o[4] = c.x; o[5] = c.y;
    float2 d = bf2x(v.w); o[6] = d.x; o[7] = d.y;
}

#define CC 96
#define SS 16
#define GG 6
#define BN_INV 0.99999500003749969f  // 1/sqrt(1+1e-5)
#define ABLK 512                     // == 2 blocks/CU exactly (VGPR 176 -> 2 waves/SIMD); no tail round
#define TOTW (ABLK * 4)

// gWB image (dwords, bf16 pairs): [0..2495] Wp2 even cols (row c2=channel/2,
// stride 52 dw, 48 used), [2496..4991] Wp2 odd cols, [4992..5303] Wpw rows.
#define WB_ODD 2496
#define WB_WPW 4992
#define WB_TOT 5304

// ---------------- kernel 0: prep (weights repack + tiny precompute) ----------------
__global__ __launch_bounds__(256) void prep_kernel(
    const float* __restrict__ Wq, const float* __restrict__ Wk, const float* __restrict__ Wv,
    const float* __restrict__ Wp2, const float* __restrict__ Ww1,
    const float* __restrict__ bp2, const float* __restrict__ bw1,
    u16* __restrict__ WcatT, unsigned int* __restrict__ gWB, float* __restrict__ cvec)
{
    int t = blockIdx.x * 256 + threadIdx.x;
    if (t < 13824) {
        // WcatT[c][j] bf16, row-major [288][96]; dword idx = c*48 + j2
        int c = t / 48, j2 = t % 48;
        const float* src = (c < 96) ? Wq : (c < 192) ? Wk : Wv;
        int cc = c % 96;
        float a = src[(2 * j2) * CC + cc];
        float b = src[(2 * j2 + 1) * CC + cc];
        ((unsigned int*)WcatT)[t] = pk2(a, b);
    } else if (t < 13824 + WB_TOT) {
        int i = t - 13824;
        if (i < WB_WPW) {
            int arr = i / WB_ODD;            // 0 = even channels, 1 = odd
            int r = i % WB_ODD;
            int c2 = r / 52, rr = r % 52;
            unsigned int d = 0;
            if (rr < 48) {
                int c = 2 * c2 + arr;
                d = pk2(Wp2[(2 * rr) * CC + c], Wp2[(2 * rr + 1) * CC + c]);
            }
            gWB[i] = d;
        } else {
            int r = i - WB_WPW;
            int g = r / 52, rr = r % 52;
            unsigned int d = 0;
            if (rr < 48) {
                float a = 0.f, b = 0.f;
                for (int c = 0; c < CC; ++c) {
                    float wg = Ww1[c * GG + g];
                    a = fmaf(Wp2[(2 * rr) * CC + c], wg, a);
                    b = fmaf(Wp2[(2 * rr + 1) * CC + c], wg, b);
                }
                d = pk2(a, b);
            }
            gWB[i] = d;
        }
    } else if (t < 13824 + WB_TOT + GG) {
        int g = t - (13824 + WB_TOT);
        float acc = bw1[g];
        for (int c = 0; c < CC; ++c)
            acc = fmaf(bp2[c], Ww1[c * GG + g], acc);
        cvec[g] = acc;
    }
}

// ---------------- kernel 0b: feat -> bf16 ----------------
__global__ __launch_bounds__(256) void fcvt_kernel(
    const float* __restrict__ feat, u16* __restrict__ featB, int total4)
{
    int i = blockIdx.x * 256 + threadIdx.x;
    if (i < total4) {
        float4 v = *(const float4*)(feat + (size_t)i * 4);
        ushort4 o;
        o.x = f2bf(v.x); o.y = f2bf(v.y); o.z = f2bf(v.z); o.w = f2bf(v.w);
        *(ushort4*)(featB + (size_t)i * 4) = o;
    }
}

// ---------------- kernel 1: fused q|k|v MFMA GEMM + epilogue (r6-proven) ----------------
#define SBS 104
__global__ __launch_bounds__(256, 2) void gemm_qkv(
    const u16* __restrict__ featB, const u16* __restrict__ WcatT,
    const float* __restrict__ bq, const float* __restrict__ gq, const float* __restrict__ betaq,
    const float* __restrict__ bk, const float* __restrict__ gk, const float* __restrict__ betak,
    const float* __restrict__ bv, const float* __restrict__ Ww1,
    u16* __restrict__ v_bf, float* __restrict__ KW1, float* __restrict__ qW1, int N)
{
    __shared__ u16 sB[288 * SBS];
    const int t = threadIdx.x;

    for (int i = t; i < 288 * 12; i += 256) {
        int row = i / 12, c8 = i % 12;
        *(float4*)(sB + row * SBS + c8 * 8) = *(const float4*)(WcatT + row * CC + c8 * 8);
    }
    __syncthreads();

    const int wave = t >> 6, lane = t & 63;
    const int m = lane & 15, quad = lane >> 4;
    const int rowbase = blockIdx.x * 64 + wave * 16;

    int arow = rowbase + m;
    if (arow >= N) arow = 0;

    short8 a[3];
    #pragma unroll
    for (int kk = 0; kk < 3; ++kk)
        a[kk] = *(const short8*)(featB + (size_t)arow * CC + kk * 32 + quad * 8);

    f32x4 acc[18];
    #pragma unroll
    for (int nt = 0; nt < 18; ++nt) acc[nt] = (f32x4){0.f, 0.f, 0.f, 0.f};

    #pragma unroll
    for (int kk = 0; kk < 3; ++kk) {
        #pragma unroll
        for (int nt = 0; nt < 18; ++nt) {
            short8 b = *(const short8*)(sB + (nt * 16 + m) * SBS + kk * 32 + quad * 8);
            acc[nt] = __builtin_amdgcn_mfma_f32_16x16x32_bf16(a[kk], b, acc[nt], 0, 0, 0);
        }
    }

    int orow[4];
    #pragma unroll
    for (int i = 0; i < 4; ++i) orow[i] = rowbase + quad * 4 + i;
    const int cloc = m;

    #pragma unroll
    for (int nt6 = 0; nt6 < 6; ++nt6) {
        int c = nt6 * 16 + cloc;
        float bvv = bv[c];
        #pragma unroll
        for (int i = 0; i < 4; ++i)
            if (orow[i] < N)
                v_bf[(size_t)orow[i] * CC + c] = f2bf(acc[12 + nt6][i] + bvv);
    }

    #pragma unroll
    for (int mat = 0; mat < 2; ++mat) {
        const float* bb_ = mat ? bk : bq;
        const float* gg_ = mat ? gk : gq;
        const float* be_ = mat ? betak : betaq;
        float red[4][6];
        #pragma unroll
        for (int i = 0; i < 4; ++i)
            #pragma unroll
            for (int g = 0; g < 6; ++g) red[i][g] = 0.f;

        #pragma unroll
        for (int nt6 = 0; nt6 < 6; ++nt6) {
            int nt = mat * 6 + nt6;
            int c = nt6 * 16 + cloc;
            float bb = bb_[c], sc = gg_[c] * BN_INV, be = be_[c];
            float w1r[6];
            #pragma unroll
            for (int g = 0; g < 6; ++g) w1r[g] = Ww1[c * GG + g];
            #pragma unroll
            for (int i = 0; i < 4; ++i) {
                float act = fmaxf(0.f, fmaf(acc[nt][i] + bb, sc, be));
                #pragma unroll
                for (int g = 0; g < 6; ++g)
                    red[i][g] = fmaf(act, w1r[g], red[i][g]);
            }
        }
        #pragma unroll
        for (int st = 1; st < 16; st <<= 1)
            #pragma unroll
            for (int i = 0; i < 4; ++i)
                #pragma unroll
                for (int g = 0; g < 6; ++g)
                    red[i][g] += __shfl_xor(red[i][g], st);

        float* dst = mat ? KW1 : qW1;
        #pragma unroll
        for (int g = 0; g < 6; ++g)
            if (cloc == g)
                #pragma unroll
                for (int i = 0; i < 4; ++i)
                    if (orow[i] < N)
                        dst[(size_t)orow[i] * 8 + g] = red[i][g];
    }
}

// ---------------- kernel 2: attention v4c — r8 + balanced grid + BN-folded consts ----------------
__global__ __launch_bounds__(256) void attn_kernel(
    const float* __restrict__ coord, const int* __restrict__ ref,
    const float* __restrict__ Wp1, const float* __restrict__ bp1, const float* __restrict__ gp, const float* __restrict__ betap,
    const float* __restrict__ bp2,
    const float* __restrict__ gw, const float* __restrict__ betaw,
    const float* __restrict__ Ww2, const float* __restrict__ bw2,
    const u16* __restrict__ v_bf, const float* __restrict__ KW1, const float* __restrict__ qW1,
    const unsigned int* __restrict__ gWB, const float* __restrict__ cvec,
    float* __restrict__ out, int N)
{
    __shared__ __align__(16) unsigned int sWB[WB_TOT];  // 21216 B
    __shared__ __align__(16) unsigned int shh[4][832];  // h bf16 pairs [s*52 + L]
    __shared__ __align__(16) uint4 swt[4][SS];          // packed softmax weights per s
    __shared__ __align__(16) float sHs[4][600];         // Hsum fp32 [g*100 + 2L]
    __shared__ __align__(16) float4 sposx[4][SS];
    __shared__ int sidxx[4][SS];

    const int t = threadIdx.x;
    for (int i = t; i < WB_TOT; i += 256) sWB[i] = gWB[i];
    __syncthreads();   // only block barrier

    const int w = t >> 6, lane = t & 63;
    const int wid = blockIdx.x * 4 + w;
    unsigned int* shw = shh[w];
    uint4* swtw = swt[w];
    float* sHsw = sHs[w];
    float4* sposw = sposx[w];
    int* sidxw = sidxx[w];

    const int  L = (lane < 48) ? lane : 47;
    const bool actv = lane < 48;
    const int  cA = 2 * L;
    const int  gL = L >> 3;
    const int  s16 = lane & 15, qq = lane >> 4;

    // BN folded into Wp1: h = relu(sp*(dot+b1) + bt) = relu(dot' + b1')
    const float spA = gp[cA] * BN_INV, spB = gp[cA + 1] * BN_INV;
    const float w1xA = Wp1[cA] * spA, w1yA = Wp1[CC + cA] * spA, w1zA = Wp1[2 * CC + cA] * spA;
    const float w1xB = Wp1[cA + 1] * spB, w1yB = Wp1[CC + cA + 1] * spB, w1zB = Wp1[2 * CC + cA + 1] * spB;
    const float b1A = fmaf(bp1[cA], spA, betap[cA]);
    const float b1B = fmaf(bp1[cA + 1], spB, betap[cA + 1]);
    const float bpA = bp2[cA], bpB = bp2[cA + 1];

    for (int n = wid; n < N; n += TOTW) {
        // ---- prefetch chain ----
        int idxreg = 0;
        if (lane < SS) {
            idxreg = ref[n * SS + s16];
            sidxw[s16] = idxreg;
        }
        unsigned int vpre[SS];
        #pragma unroll
        for (int s = 0; s < SS; ++s) {
            int jj = sidxw[s];                       // wave-private, in-order DS
            vpre[s] = *(const unsigned int*)(v_bf + (size_t)jj * CC + cA);
        }
        float4 kAv = {0,0,0,0}; float2 kBv = {0,0};
        float4 qAv = {0,0,0,0}; float2 qBv = {0,0};
        if (lane < SS) {
            int j = idxreg;
            float4 P;
            P.x = coord[j * 3 + 0] - coord[n * 3 + 0];
            P.y = coord[j * 3 + 1] - coord[n * 3 + 1];
            P.z = coord[j * 3 + 2] - coord[n * 3 + 2];
            P.w = 0.f;
            sposw[s16] = P;
            const float* kr = KW1 + (size_t)idxreg * 8;
            kAv = *(const float4*)kr; kBv = *(const float2*)(kr + 4);
            const float* qr = qW1 + (size_t)n * 8;
            qAv = *(const float4*)qr; qBv = *(const float2*)(qr + 4);
        }

        // ---- stage 1: h = relu(pos@Wp1' + b1') -> packed bf16 pairs ----
        if (actv) {
            #pragma unroll
            for (int s = 0; s < SS; ++s) {
                float4 P = sposw[s];                 // broadcast b128
                float hA = fmaxf(0.f, fmaf(P.x, w1xA, fmaf(P.y, w1yA, fmaf(P.z, w1zA, b1A))));
                float hB = fmaxf(0.f, fmaf(P.x, w1xB, fmaf(P.y, w1yB, fmaf(P.z, w1zB, b1B))));
                shw[s * 52 + L] = pk2(hA, hB);
            }
        }

        // ---- stage 2: logits (4 lanes per neighbor, 24-ch slices) ----
        {
            const unsigned int* hrow = shw + 52 * s16 + 12 * qq;
            float hg[24];
            bf8x(*(const uint4*)(hrow), hg);
            bf8x(*(const uint4*)(hrow + 4), hg + 8);
            bf8x(*(const uint4*)(hrow + 8), hg + 16);

            float acc[GG];
            #pragma unroll
            for (int g = 0; g < GG; ++g) {
                const unsigned int* wr = sWB + WB_WPW + g * 52 + 12 * qq;
                float wg[24];
                bf8x(*(const uint4*)(wr), wg);
                bf8x(*(const uint4*)(wr + 4), wg + 8);
                bf8x(*(const uint4*)(wr + 8), wg + 16);
                float a = 0.f;
                #pragma unroll
                for (int u = 0; u < 24; ++u)
                    a = fmaf(hg[u], wg[u], a);
                acc[g] = a;
            }
            #pragma unroll
            for (int g = 0; g < GG; ++g) {
                acc[g] += __shfl_xor(acc[g], 16);
                acc[g] += __shfl_xor(acc[g], 32);
            }

            if (lane < SS) {
                float tv[GG];
                tv[0] = acc[0] + kAv.x - qAv.x + cvec[0];
                tv[1] = acc[1] + kAv.y - qAv.y + cvec[1];
                tv[2] = acc[2] + kAv.z - qAv.z + cvec[2];
                tv[3] = acc[3] + kAv.w - qAv.w + cvec[3];
                tv[4] = acc[4] + kBv.x - qBv.x + cvec[4];
                tv[5] = acc[5] + kBv.y - qBv.y + cvec[5];
                float a6[GG];
                #pragma unroll
                for (int g = 0; g < GG; ++g)
                    a6[g] = fmaxf(0.f, fmaf(tv[g], gw[g] * BN_INV, betaw[g]));
                float e[GG];
                #pragma unroll
                for (int gg2 = 0; gg2 < GG; ++gg2) {
                    float lv = bw2[gg2];
                    #pragma unroll
                    for (int g2 = 0; g2 < GG; ++g2)
                        lv = fmaf(a6[g2], Ww2[g2 * GG + gg2], lv);
                    e[gg2] = __expf(lv);
                }
                float wgt[GG];
                #pragma unroll
                for (int g = 0; g < GG; ++g) {
                    float ssum = e[g];
                    ssum += __shfl_xor(ssum, 1);
                    ssum += __shfl_xor(ssum, 2);
                    ssum += __shfl_xor(ssum, 4);
                    ssum += __shfl_xor(ssum, 8);
                    wgt[g] = e[g] / ssum;
                }
                uint4 wt;
                wt.x = pk2(wgt[0], wgt[1]);
                wt.y = pk2(wgt[2], wgt[3]);
                wt.z = pk2(wgt[4], wgt[5]);
                wt.w = 0u;
                swtw[s16] = wt;
            }
        }

        // ---- stage 3+4: Hsum + v-part fused ----
        float accA = bpA, accB = bpB;
        {
            float hsA[GG] = {0.f,0.f,0.f,0.f,0.f,0.f};
            float hsB[GG] = {0.f,0.f,0.f,0.f,0.f,0.f};
            #pragma unroll
            for (int s = 0; s < SS; ++s) {
                uint4 wt = swtw[s];                  // broadcast b128
                float2 w01 = bf2x(wt.x), w23 = bf2x(wt.y), w45 = bf2x(wt.z);
                float2 h2 = bf2x(shw[s * 52 + L]);
                hsA[0] = fmaf(w01.x, h2.x, hsA[0]); hsB[0] = fmaf(w01.x, h2.y, hsB[0]);
                hsA[1] = fmaf(w01.y, h2.x, hsA[1]); hsB[1] = fmaf(w01.y, h2.y, hsB[1]);
                hsA[2] = fmaf(w23.x, h2.x, hsA[2]); hsB[2] = fmaf(w23.x, h2.y, hsB[2]);
                hsA[3] = fmaf(w23.y, h2.x, hsA[3]); hsB[3] = fmaf(w23.y, h2.y, hsB[3]);
                hsA[4] = fmaf(w45.x, h2.x, hsA[4]); hsB[4] = fmaf(w45.x, h2.y, hsB[4]);
                hsA[5] = fmaf(w45.y, h2.x, hsA[5]); hsB[5] = fmaf(w45.y, h2.y, hsB[5]);
                float wsel = (gL < 2) ? (gL == 0 ? w01.x : w01.y)
                           : (gL < 4) ? (gL == 2 ? w23.x : w23.y)
                                      : (gL == 4 ? w45.x : w45.y);
                float2 v2 = bf2x(vpre[s]);
                accA = fmaf(v2.x, wsel, accA);
                accB = fmaf(v2.y, wsel, accB);
            }
            if (actv) {
                #pragma unroll
                for (int g = 0; g < GG; ++g)
                    *(float2*)(sHsw + g * 100 + cA) = make_float2(hsA[g], hsB[g]);
            }
        }

        // ---- stage 5: out = v-part + Hsum[gL] @ Wp2 cols ----
        if (actv) {
            const float* hrg = sHsw + gL * 100;
            const unsigned int* wrE = sWB + L * 52;            // even channel cA
            const unsigned int* wrO = sWB + WB_ODD + L * 52;   // odd channel cA+1
            #pragma unroll
            for (int u = 0; u < 12; ++u) {
                float4 hb0 = *(const float4*)(hrg + 8 * u);
                float4 hb1 = *(const float4*)(hrg + 8 * u + 4);
                float we[8], wo[8];
                bf8x(*(const uint4*)(wrE + 4 * u), we);
                bf8x(*(const uint4*)(wrO + 4 * u), wo);
                accA = fmaf(hb0.x, we[0], accA); accB = fmaf(hb0.x, wo[0], accB);
                accA = fmaf(hb0.y, we[1], accA); accB = fmaf(hb0.y, wo[1], accB);
                accA = fmaf(hb0.z, we[2], accA); accB = fmaf(hb0.z, wo[2], accB);
                accA = fmaf(hb0.w, we[3], accA); accB = fmaf(hb0.w, wo[3], accB);
                accA = fmaf(hb1.x, we[4], accA); accB = fmaf(hb1.x, wo[4], accB);
                accA = fmaf(hb1.y, we[5], accA); accB = fmaf(hb1.y, wo[5], accB);
                accA = fmaf(hb1.z, we[6], accA); accB = fmaf(hb1.z, wo[6], accB);
                accA = fmaf(hb1.w, we[7], accA); accB = fmaf(hb1.w, wo[7], accB);
            }
            *(float2*)(out + (size_t)n * CC + cA) = make_float2(accA, accB);
        }
    }
}

extern "C" void kernel_launch(void* const* d_in, const int* in_sizes, int n_in,
                              void* d_out, int out_size, void* d_ws, size_t ws_size,
                              hipStream_t stream) {
    const float* feat  = (const float*)d_in[0];
    const float* coord = (const float*)d_in[1];
    const int*   ref   = (const int*)d_in[2];
    const float* Wq = (const float*)d_in[3],  *bq = (const float*)d_in[4],  *gq = (const float*)d_in[5],  *betaq = (const float*)d_in[6];
    const float* Wk = (const float*)d_in[7],  *bk = (const float*)d_in[8],  *gk = (const float*)d_in[9],  *betak = (const float*)d_in[10];
    const float* Wv = (const float*)d_in[11], *bv = (const float*)d_in[12];
    const float* Wp1 = (const float*)d_in[13], *bp1 = (const float*)d_in[14], *gp = (const float*)d_in[15], *betap = (const float*)d_in[16];
    const float* Wp2 = (const float*)d_in[17], *bp2 = (const float*)d_in[18];
    const float* Ww1 = (const float*)d_in[19], *bw1 = (const float*)d_in[20], *gw = (const float*)d_in[21], *betaw = (const float*)d_in[22];
    const float* Ww2 = (const float*)d_in[23], *bw2 = (const float*)d_in[24];

    const int N = in_sizes[0] / CC;   // 50000

    // workspace (~23 MB)
    float* wsf = (float*)d_ws;
    float* KW1 = wsf;                                  // N*8 f32
    float* qW1 = KW1 + (size_t)N * 8;                  // N*8 f32
    float* cvec = qW1 + (size_t)N * 8;                 // 6 (pad 32)
    unsigned int* gWB = (unsigned int*)(cvec + 32);    // 5304 (pad 5312)
    u16* WcatT = (u16*)(gWB + 5312);                   // 288*96 bf16
    u16* featB = WcatT + 288 * CC;                     // N*96 bf16
    u16* v_bf = featB + (size_t)N * CC;                // N*96 bf16

    const int prep_total = 13824 + WB_TOT + GG;
    prep_kernel<<<dim3((prep_total + 255) / 256), dim3(256), 0, stream>>>(
        Wq, Wk, Wv, Wp2, Ww1, bp2, bw1, WcatT, gWB, cvec);

    const int total4 = N * CC / 4;
    fcvt_kernel<<<dim3((total4 + 255) / 256), dim3(256), 0, stream>>>(feat, featB, total4);

    gemm_qkv<<<dim3((N + 63) / 64), dim3(256), 0, stream>>>(
        featB, WcatT, bq, gq, betaq, bk, gk, betak, bv, Ww1,
        v_bf, KW1, qW1, N);

    attn_kernel<<<dim3(ABLK), dim3(256), 0, stream>>>(
        coord, ref, Wp1, bp1, gp, betap, bp2, gw, betaw, Ww2, bw2,
        v_bf, KW1, qW1, gWB, cvec, (float*)d_out, N);
}